// Round 4
// baseline (45.056 us; speedup 1.0000x reference)
//
#include <hip/hip_runtime.h>

#define CLS 8
#define BATCH 8
#define BPB 256                      // blocks per batch -> 2048 blocks, 1024 px/block
#define PXB 1024
#define NSLICE 8
#define LOG2E 1.442695040888963f
#define LN2   0.693147180559945f

// select compile-time component e of a float4/int4
#define F4C(v, e) ((e) == 0 ? (v).x : (e) == 1 ? (v).y : (e) == 2 ? (v).z : (v).w)

__device__ __forceinline__ float wave_reduce(float v) {
#pragma unroll
    for (int off = 32; off > 0; off >>= 1) v += __shfl_xor(v, off);
    return v;
}

// async 16B-per-lane global -> LDS (wave-uniform base + lane*16, linear dest)
__device__ __forceinline__ void gload16(const void* g, void* l) {
    __builtin_amdgcn_global_load_lds(
        (const __attribute__((address_space(1))) unsigned int*)g,
        (__attribute__((address_space(3))) unsigned int*)l, 16, 0, 0);
}

__global__ __launch_bounds__(256) void jce_main(
    const float* __restrict__ pred, const int* __restrict__ tgt,
    float* __restrict__ Spart, float* __restrict__ nPart, float* __restrict__ lsePart,
    int N)
{
    __shared__ float predT[CLS][PXB];    // 32 KB, [channel][pixel] linear rows
    __shared__ int   tgtT[PXB];          // 4 KB
    __shared__ float redS[4][64];
    __shared__ float redl[4];
    __shared__ int   redc[4][CLS];

    const int tid  = threadIdx.x;
    const int b    = blockIdx.x & (BATCH - 1);   // consecutive blocks -> different batch (+8MB)
    const int blk  = blockIdx.x >> 3;
    const int base = blk * PXB;
    const float* pb = pred + (size_t)b * CLS * N + base;
    const int*   tb = tgt  + (size_t)b * N + base;
    const int wv   = tid >> 6;
    const int lane = tid & 63;

    // cooperative staging: rotate channel order per wave so concurrent loads
    // hit different 1MB-stride classes (DRAM channel spread)
    gload16(tb + tid * 4, &tgtT[tid * 4]);
#pragma unroll
    for (int ii = 0; ii < CLS; ++ii) {
        const int c = (2 * wv + ii) & 7;
        gload16(pb + (size_t)c * N + tid * 4, &predT[c][tid * 4]);
    }
    __syncthreads();   // compiler emits vmcnt(0) drain before barrier

    // read back 4 pixels x 8 channels (contiguous ds_read_b128, conflict-free)
    float4 p4[CLS];
#pragma unroll
    for (int c = 0; c < CLS; ++c)
        p4[c] = *reinterpret_cast<const float4*>(&predT[c][tid * 4]);
    const int4 t4 = *reinterpret_cast<const int4*>(&tgtT[tid * 4]);

    float acc[64];                       // acc[i*8+k] = sum_{p: t=k} pred[i]
#pragma unroll
    for (int j = 0; j < 64; ++j) acc[j] = 0.f;
    float accl = 0.f;                    // sum log2(sum_i 2^(pc_i*log2e))
    int cnt[CLS] = {0, 0, 0, 0, 0, 0, 0, 0};

#define COMPUTE_E(e) do {                                                       \
        float _pc[CLS];                                                         \
        _Pragma("unroll")                                                       \
        for (int _i = 0; _i < CLS; ++_i) _pc[_i] = F4C(p4[_i], e);              \
        const int _t = F4C(t4, e);                                              \
        float _s = 0.f;                                                         \
        _Pragma("unroll")                                                       \
        for (int _i = 0; _i < CLS; ++_i) _s += exp2f(_pc[_i] * LOG2E);          \
        accl += log2f(_s);                                                      \
        _Pragma("unroll")                                                       \
        for (int _k = 0; _k < CLS; ++_k) {                                      \
            const bool _isk = (_t == _k);                                       \
            cnt[_k] += __popcll(__ballot(_isk));                                \
            const float _pm = _isk ? 1.f : 0.f;                                 \
            _Pragma("unroll")                                                   \
            for (int _i = 0; _i < CLS; ++_i)                                    \
                acc[_i * 8 + _k] = fmaf(_pm, _pc[_i], acc[_i * 8 + _k]);        \
        }                                                                       \
    } while (0)

    COMPUTE_E(0);
    COMPUTE_E(1);
    COMPUTE_E(2);
    COMPUTE_E(3);
#undef COMPUTE_E

    // split-vector butterfly: reduce the 64-entry vector across 64 lanes;
    // lane l ends holding wave-total of entry bitrev6(l)
#pragma unroll
    for (int s6 = 0; s6 < 6; ++s6) {
        const int d = 1 << s6;
        const int half = 32 >> s6;
        const bool hi = (lane & d) != 0;
#pragma unroll
        for (int j = 0; j < half; ++j) {
            const float keep = hi ? acc[j + half] : acc[j];
            const float send = hi ? acc[j] : acc[j + half];
            acc[j] = keep + __shfl_xor(send, d);
        }
    }
    const int e = ((lane & 1) << 5) | ((lane & 2) << 3) | ((lane & 4) << 1) |
                  ((lane & 8) >> 1) | ((lane & 16) >> 3) | ((lane & 32) >> 5);

    redS[wv][e] = acc[0];
    const float lsum = wave_reduce(accl);
    if (lane == 0) {
        redl[wv] = lsum;
#pragma unroll
        for (int k = 0; k < CLS; ++k) redc[wv][k] = cnt[k];
    }
    __syncthreads();

    const int sl = blk & (NSLICE - 1);   // spread atomics over 8 slice copies
    if (tid < 64) {
        const float v = redS[0][tid] + redS[1][tid] + redS[2][tid] + redS[3][tid];
        atomicAdd(&Spart[(sl * BATCH + b) * 64 + tid], v);
    } else if (tid < 64 + CLS) {
        const int k = tid - 64;
        const float v = (float)(redc[0][k] + redc[1][k] + redc[2][k] + redc[3][k]);
        atomicAdd(&nPart[(sl * BATCH + b) * CLS + k], v);
    } else if (tid == 64 + CLS) {
        const float v = (redl[0] + redl[1] + redl[2] + redl[3]) * LN2;
        atomicAdd(&lsePart[sl], v);
    }
}

// Epilogue: A = S/n; j[b] = -sum_{i!=k} w[i,k]*log(0.5+0.5*(A[i,i]-A[i,k]));
// ce = (sum(lse) - sum_b trace(S_b)) / (B*N);  out[b] = j[b] + ce
__global__ __launch_bounds__(64) void jce_final(
    const float* __restrict__ Spart, const float* __restrict__ nPart,
    const float* __restrict__ lsePart, const float* __restrict__ w,
    float* __restrict__ out, int N)
{
    const int b   = blockIdx.x;
    const int tid = threadIdx.x;           // 64 threads = (i,k)
    const int i = tid >> 3, k = tid & 7;

    float Ssum = 0.f, nsum = 0.f, tv = 0.f;
#pragma unroll
    for (int sl = 0; sl < NSLICE; ++sl) {
        Ssum += Spart[(sl * BATCH + b) * 64 + tid];
        nsum += nPart[(sl * BATCH + b) * CLS + k];
        tv   += Spart[(sl * BATCH + (tid >> 3)) * 64 + (tid & 7) * 9];  // trace terms
    }
    const float A = Ssum / nsum;
    __shared__ float lA[64];
    lA[tid] = A;
    __syncthreads();
    const float diag = lA[i * 9];

    float term = 0.f;
    if (i != k)
        term = w[tid] * (log2f(0.5f + 0.5f * (diag - A)) * LN2);

    const float termSum = wave_reduce(term);
    const float trAll   = wave_reduce(tv);

    if (tid == 0) {
        float lse = 0.f;
#pragma unroll
        for (int sl = 0; sl < NSLICE; ++sl) lse += lsePart[sl];
        const float ce = (lse - trAll) / ((float)BATCH * (float)N);
        out[b] = -termSum + ce;
    }
}

extern "C" void kernel_launch(void* const* d_in, const int* in_sizes, int n_in,
                              void* d_out, int out_size, void* d_ws, size_t ws_size,
                              hipStream_t stream) {
    const float* pred = (const float*)d_in[0];
    const int*   tgt  = (const int*)d_in[1];
    const float* w    = (const float*)d_in[2];
    float* out = (float*)d_out;

    const int N = in_sizes[1] / BATCH;        // H*W = 262144

    float* Spart   = (float*)d_ws;                        // NSLICE*BATCH*64
    float* nPart   = Spart + NSLICE * BATCH * 64;         // NSLICE*BATCH*8
    float* lsePart = nPart + NSLICE * BATCH * CLS;        // NSLICE

    hipMemsetAsync(d_ws, 0,
                   (size_t)(NSLICE * BATCH * 64 + NSLICE * BATCH * CLS + NSLICE) * sizeof(float),
                   stream);

    jce_main<<<dim3(BATCH * BPB), dim3(256), 0, stream>>>(pred, tgt, Spart, nPart, lsePart, N);
    jce_final<<<dim3(BATCH), dim3(64), 0, stream>>>(Spart, nPart, lsePart, w, out, N);
}

// Round 5
// 41.475 us; speedup vs baseline: 1.0864x; 1.0864x over previous
//
#include <hip/hip_runtime.h>

#define CLS 8
#define BATCH 8
#define BPB 128                      // blocks per batch -> 1024 blocks, 2048 px/block
#define NSLICE 16
#define LOG2E 1.442695040888963f
#define LN2   0.693147180559945f

// select compile-time component e of a float2/int2
#define F2C(v, e) ((e) == 0 ? (v).x : (v).y)

__device__ __forceinline__ float wave_reduce(float v) {
#pragma unroll
    for (int off = 32; off > 0; off >>= 1) v += __shfl_xor(v, off);
    return v;
}

__global__ __launch_bounds__(256, 4) void jce_main(
    const float* __restrict__ pred, const int* __restrict__ tgt,
    float* __restrict__ Spart, float* __restrict__ nPart, float* __restrict__ lsePart,
    int N)
{
    const int tid  = threadIdx.x;
    const int b    = blockIdx.x & (BATCH - 1);   // consecutive blocks -> different batch
    const int blk  = blockIdx.x >> 3;
    const int base = blk * (N / BPB);            // 2048 px per block
    const float* pb = pred + (size_t)b * CLS * N;
    const int*   tb = tgt  + (size_t)b * N;

    float acc[64];                               // acc[i*8+k] = sum_{p: t=k} pred[i]
#pragma unroll
    for (int j = 0; j < 64; ++j) acc[j] = 0.f;
    float accl = 0.f;                            // sum log2(sum_i 2^(pc_i*log2e))
    int cnt[CLS] = {0, 0, 0, 0, 0, 0, 0, 0};     // wave-uniform class counts (SGPR)

    // 4 groups of float2 (2 px) per thread; depth-2 register pipeline.
    // Buffer = 8 x float2 + int2 = 18 VGPR; two buffers + acc64 + temps ~ 115 VGPR.
    float2 pA[CLS], pB[CLS];
    int2 tA, tB;

#define LOADG(P, T, g) do {                                                     \
        const int _pix = base + (g) * 512 + tid * 2;                            \
        _Pragma("unroll")                                                       \
        for (int _i = 0; _i < CLS; ++_i)                                        \
            (P)[_i] = *reinterpret_cast<const float2*>(pb + (size_t)_i * N + _pix); \
        (T) = *reinterpret_cast<const int2*>(tb + _pix);                        \
    } while (0)

#define COMPUTE_E(P, T, e) do {                                                 \
        float _pc[CLS];                                                         \
        _Pragma("unroll")                                                       \
        for (int _i = 0; _i < CLS; ++_i) _pc[_i] = F2C((P)[_i], e);             \
        const int _t = F2C((T), e);                                             \
        float _s = 0.f;                                                         \
        _Pragma("unroll")                                                       \
        for (int _i = 0; _i < CLS; ++_i) _s += exp2f(_pc[_i] * LOG2E);          \
        accl += log2f(_s);                                                      \
        _Pragma("unroll")                                                       \
        for (int _k = 0; _k < CLS; ++_k) {                                      \
            const bool _isk = (_t == _k);                                       \
            cnt[_k] += __popcll(__ballot(_isk));                                \
            const float _pm = _isk ? 1.f : 0.f;                                 \
            _Pragma("unroll")                                                   \
            for (int _i = 0; _i < CLS; ++_i)                                    \
                acc[_i * 8 + _k] = fmaf(_pm, _pc[_i], acc[_i * 8 + _k]);        \
        }                                                                       \
    } while (0)

    LOADG(pA, tA, 0);
    LOADG(pB, tB, 1);       // 18 loads in flight before first wait
    COMPUTE_E(pA, tA, 0);
    COMPUTE_E(pA, tA, 1);
    LOADG(pA, tA, 2);       // refill A while B still in flight / being consumed
    COMPUTE_E(pB, tB, 0);
    COMPUTE_E(pB, tB, 1);
    LOADG(pB, tB, 3);
    COMPUTE_E(pA, tA, 0);
    COMPUTE_E(pA, tA, 1);
    COMPUTE_E(pB, tB, 0);
    COMPUTE_E(pB, tB, 1);

#undef LOADG
#undef COMPUTE_E

    // split-vector butterfly: reduce the 64-entry register vector across 64 lanes;
    // lane l ends holding the wave-total of entry bitrev6(l)
    const int lane = tid & 63;
#pragma unroll
    for (int s6 = 0; s6 < 6; ++s6) {
        const int d = 1 << s6;
        const int half = 32 >> s6;
        const bool hi = (lane & d) != 0;
#pragma unroll
        for (int j = 0; j < half; ++j) {
            const float keep = hi ? acc[j + half] : acc[j];
            const float send = hi ? acc[j] : acc[j + half];
            acc[j] = keep + __shfl_xor(send, d);
        }
    }
    const int e = ((lane & 1) << 5) | ((lane & 2) << 3) | ((lane & 4) << 1) |
                  ((lane & 8) >> 1) | ((lane & 16) >> 3) | ((lane & 32) >> 5);

    __shared__ float redS[4][64];
    __shared__ float redl[4];
    __shared__ int   redc[4][CLS];
    const int wv = tid >> 6;

    redS[wv][e] = acc[0];
    const float lsum = wave_reduce(accl);
    if (lane == 0) {
        redl[wv] = lsum;
#pragma unroll
        for (int k = 0; k < CLS; ++k) redc[wv][k] = cnt[k];
    }
    __syncthreads();

    const int sl = blk & (NSLICE - 1);   // spread atomics over 16 slice copies
    if (tid < 64) {
        const float v = redS[0][tid] + redS[1][tid] + redS[2][tid] + redS[3][tid];
        atomicAdd(&Spart[(sl * BATCH + b) * 64 + tid], v);
    } else if (tid < 64 + CLS) {
        const int k = tid - 64;
        const float v = (float)(redc[0][k] + redc[1][k] + redc[2][k] + redc[3][k]);
        atomicAdd(&nPart[(sl * BATCH + b) * CLS + k], v);
    } else if (tid == 64 + CLS) {
        const float v = (redl[0] + redl[1] + redl[2] + redl[3]) * LN2;
        atomicAdd(&lsePart[sl], v);
    }
}

// Epilogue: A = S/n; j[b] = -sum_{i!=k} w[i,k]*log(0.5+0.5*(A[i,i]-A[i,k]));
// ce = (sum(lse) - sum_b trace(S_b)) / (B*N);  out[b] = j[b] + ce
__global__ __launch_bounds__(64) void jce_final(
    const float* __restrict__ Spart, const float* __restrict__ nPart,
    const float* __restrict__ lsePart, const float* __restrict__ w,
    float* __restrict__ out, int N)
{
    const int b   = blockIdx.x;
    const int tid = threadIdx.x;           // 64 threads = (i,k)
    const int i = tid >> 3, k = tid & 7;

    float Ssum = 0.f, nsum = 0.f, tv = 0.f;
#pragma unroll
    for (int sl = 0; sl < NSLICE; ++sl) {
        Ssum += Spart[(sl * BATCH + b) * 64 + tid];
        nsum += nPart[(sl * BATCH + b) * CLS + k];
        tv   += Spart[(sl * BATCH + (tid >> 3)) * 64 + (tid & 7) * 9];  // trace terms
    }
    const float A = Ssum / nsum;
    __shared__ float lA[64];
    lA[tid] = A;
    __syncthreads();
    const float diag = lA[i * 9];

    float term = 0.f;
    if (i != k)
        term = w[tid] * (log2f(0.5f + 0.5f * (diag - A)) * LN2);

    const float termSum = wave_reduce(term);
    const float trAll   = wave_reduce(tv);

    if (tid == 0) {
        float lse = 0.f;
#pragma unroll
        for (int sl = 0; sl < NSLICE; ++sl) lse += lsePart[sl];
        const float ce = (lse - trAll) / ((float)BATCH * (float)N);
        out[b] = -termSum + ce;
    }
}

extern "C" void kernel_launch(void* const* d_in, const int* in_sizes, int n_in,
                              void* d_out, int out_size, void* d_ws, size_t ws_size,
                              hipStream_t stream) {
    const float* pred = (const float*)d_in[0];
    const int*   tgt  = (const int*)d_in[1];
    const float* w    = (const float*)d_in[2];
    float* out = (float*)d_out;

    const int N = in_sizes[1] / BATCH;        // H*W = 262144

    float* Spart   = (float*)d_ws;                        // NSLICE*BATCH*64
    float* nPart   = Spart + NSLICE * BATCH * 64;         // NSLICE*BATCH*8
    float* lsePart = nPart + NSLICE * BATCH * CLS;        // NSLICE

    hipMemsetAsync(d_ws, 0,
                   (size_t)(NSLICE * BATCH * 64 + NSLICE * BATCH * CLS + NSLICE) * sizeof(float),
                   stream);

    jce_main<<<dim3(BATCH * BPB), dim3(256), 0, stream>>>(pred, tgt, Spart, nPart, lsePart, N);
    jce_final<<<dim3(BATCH), dim3(64), 0, stream>>>(Spart, nPart, lsePart, w, out, N);
}